// Round 1
// baseline (1150.444 us; speedup 1.0000x reference)
//
#include <hip/hip_runtime.h>
#include <hip/hip_bf16.h>
#include <math.h>

#define NF 128          // feature dim F == hidden dim H == 128
#define RS 132          // LDS row stride in floats (16B-aligned, conflict-free)

// ---------------- K0: per-segment start/count table ----------------
__global__ void k_segtab(const int* __restrict__ ptr, const int* __restrict__ split,
                         int nseg, int* __restrict__ segstart, int* __restrict__ segcnt) {
    int s = blockIdx.x * blockDim.x + threadIdx.x;
    if (s >= nseg) return;
    int g = s >> 1;
    int base = ptr[g];
    int sp = split[g];
    segstart[s] = (s & 1) ? base + sp : base;
    segcnt[s]   = (s & 1) ? (ptr[g + 1] - base - sp) : sp;
}

// ---------------- K1: per-node (seg,loc) + deg init ----------------
__global__ void k_node(const int* __restrict__ ptr, const int* __restrict__ split,
                       int nB, int N, unsigned* __restrict__ segloc, float* __restrict__ deg) {
    int i = blockIdx.x * blockDim.x + threadIdx.x;
    if (i >= N) return;
    // upper_bound over ptr[0..nB]
    int lo = 0, hi = nB + 1;
    while (lo < hi) { int mid = (lo + hi) >> 1; if (ptr[mid] <= i) lo = mid + 1; else hi = mid; }
    int g = lo - 1;
    int local = i - ptr[g];
    int sp = split[g];
    int drug = (local >= sp) ? 1 : 0;
    int seg = 2 * g + drug;
    int loc = local - (drug ? sp : 0);
    segloc[i] = ((unsigned)seg << 8) | (unsigned)loc;
    deg[i] = 1.0f;   // self-loop
}

// ---------------- K2: degree accumulation ----------------
__global__ void k_deg(const int* __restrict__ src, const int* __restrict__ dst, int E,
                      const unsigned* __restrict__ segloc, float* __restrict__ deg) {
    int e = blockIdx.x * blockDim.x + threadIdx.x;
    if (e >= E) return;
    int s = src[e], d = dst[e];
    if ((segloc[s] >> 8) == (segloc[d] >> 8)) atomicAdd(&deg[d], 1.0f);
}

// ---------------- K3: dinv (in-place) + adjacency diagonal ----------------
__global__ void k_dinv(int N, float* __restrict__ deg, const unsigned* __restrict__ segloc,
                       float* __restrict__ A) {
    int i = blockIdx.x * blockDim.x + threadIdx.x;
    if (i >= N) return;
    float dv = rsqrtf(deg[i]);
    deg[i] = dv;                       // deg now holds dinv
    unsigned sl = segloc[i];
    int seg = (int)(sl >> 8), loc = (int)(sl & 255u);
    A[(size_t)seg * 1024 + loc * 32 + loc] = dv * dv;   // A pre-zeroed
}

// ---------------- K5: adjacency off-diagonal (atomic) ----------------
__global__ void k_adj(const int* __restrict__ src, const int* __restrict__ dst, int E,
                      const unsigned* __restrict__ segloc, const float* __restrict__ dinv,
                      float* __restrict__ A) {
    int e = blockIdx.x * blockDim.x + threadIdx.x;
    if (e >= E) return;
    int s = src[e], d = dst[e];
    unsigned ss = segloc[s], dd = segloc[d];
    if ((ss >> 8) != (dd >> 8)) return;
    float n = dinv[s] * dinv[d];
    atomicAdd(&A[(size_t)(ss >> 8) * 1024 + (int)(dd & 255u) * 32 + (int)(ss & 255u)], n);
}

// ---------------- helpers ----------------
__device__ __forceinline__ void fma16(float* acc, float a, const float4& w0,
                                      const float4& w1, const float4& w2, const float4& w3) {
    acc[0]  += a * w0.x; acc[1]  += a * w0.y; acc[2]  += a * w0.z; acc[3]  += a * w0.w;
    acc[4]  += a * w1.x; acc[5]  += a * w1.y; acc[6]  += a * w1.z; acc[7]  += a * w1.w;
    acc[8]  += a * w2.x; acc[9]  += a * w2.y; acc[10] += a * w2.z; acc[11] += a * w2.w;
    acc[12] += a * w3.x; acc[13] += a * w3.y; acc[14] += a * w3.z; acc[15] += a * w3.w;
}

// ---------------- K6: fused 2-layer GCN + mean pool (one block per segment) ----------------
__global__ void __launch_bounds__(256, 4) k_gcn(
    const float* __restrict__ x, const float* __restrict__ A,
    const int* __restrict__ segstart, const int* __restrict__ segcnt,
    const float* __restrict__ W1, const float* __restrict__ b1,
    const float* __restrict__ W2, const float* __restrict__ b2,
    float* __restrict__ pooled) {
    __shared__ float bufA[32 * RS];
    __shared__ float bufB[32 * RS];
    __shared__ float Al[32 * 33];

    int s = blockIdx.x;
    int t = threadIdx.x;
    int start = segstart[s], cnt = segcnt[s];

    // load 32x32 adjacency block (padded stride 33)
    for (int i = t; i < 1024; i += 256)
        Al[(i >> 5) * 33 + (i & 31)] = A[(size_t)s * 1024 + i];

    // load X_s (32 x 128), zero-pad missing rows
    for (int i = t; i < 32 * 32; i += 256) {
        int r = i >> 5, c4 = i & 31;
        float4 v = make_float4(0.f, 0.f, 0.f, 0.f);
        if (r < cnt) v = *reinterpret_cast<const float4*>(x + (size_t)(start + r) * NF + c4 * 4);
        *reinterpret_cast<float4*>(&bufA[r * RS + c4 * 4]) = v;
    }
    __syncthreads();

    const int r  = t >> 3;          // 0..31 output row
    const int cb = (t & 7) * 16;    // column base, 16 cols per thread

    #pragma unroll 1
    for (int layer = 0; layer < 2; ++layer) {
        const float* W  = layer ? W2 : W1;
        const float* bb = layer ? b2 : b1;

        // phase 1: bufB = bufA @ W   (32x128 @ 128x128, this thread: row r, cols cb..cb+15)
        float acc[16];
        #pragma unroll
        for (int i = 0; i < 16; ++i) acc[i] = 0.f;
        #pragma unroll 1
        for (int k4 = 0; k4 < 32; ++k4) {
            float4 a4 = *reinterpret_cast<const float4*>(&bufA[r * RS + k4 * 4]);
            const float* Wk = W + (k4 * 4) * NF + cb;
            {
                const float4* w = reinterpret_cast<const float4*>(Wk);
                fma16(acc, a4.x, w[0], w[1], w[2], w[3]);
            }
            {
                const float4* w = reinterpret_cast<const float4*>(Wk + NF);
                fma16(acc, a4.y, w[0], w[1], w[2], w[3]);
            }
            {
                const float4* w = reinterpret_cast<const float4*>(Wk + 2 * NF);
                fma16(acc, a4.z, w[0], w[1], w[2], w[3]);
            }
            {
                const float4* w = reinterpret_cast<const float4*>(Wk + 3 * NF);
                fma16(acc, a4.w, w[0], w[1], w[2], w[3]);
            }
        }
        #pragma unroll
        for (int i = 0; i < 4; ++i)
            *reinterpret_cast<float4*>(&bufB[r * RS + cb + i * 4]) =
                make_float4(acc[i*4], acc[i*4+1], acc[i*4+2], acc[i*4+3]);
        __syncthreads();

        // phase 2: bufA = relu(Al @ bufB + b)
        float o[16];
        {
            const float4* bv = reinterpret_cast<const float4*>(bb + cb);
            float4 b0 = bv[0], b1v = bv[1], b2v = bv[2], b3 = bv[3];
            o[0]=b0.x; o[1]=b0.y; o[2]=b0.z; o[3]=b0.w;
            o[4]=b1v.x; o[5]=b1v.y; o[6]=b1v.z; o[7]=b1v.w;
            o[8]=b2v.x; o[9]=b2v.y; o[10]=b2v.z; o[11]=b2v.w;
            o[12]=b3.x; o[13]=b3.y; o[14]=b3.z; o[15]=b3.w;
        }
        #pragma unroll 2
        for (int j = 0; j < 32; ++j) {
            float av = Al[r * 33 + j];
            const float4* h = reinterpret_cast<const float4*>(&bufB[j * RS + cb]);
            fma16(o, av, h[0], h[1], h[2], h[3]);
        }
        #pragma unroll
        for (int i = 0; i < 16; ++i) o[i] = o[i] > 0.f ? o[i] : 0.f;
        #pragma unroll
        for (int i = 0; i < 4; ++i)
            *reinterpret_cast<float4*>(&bufA[r * RS + cb + i * 4]) =
                make_float4(o[i*4], o[i*4+1], o[i*4+2], o[i*4+3]);
        __syncthreads();
    }

    // mean pool over valid rows -> pooled[s][0..127]
    if (t < 128) {
        float sum = 0.f;
        for (int rr = 0; rr < cnt; ++rr) sum += bufA[rr * RS + t];
        pooled[(size_t)s * 128 + t] = sum / (float)(cnt > 0 ? cnt : 1);
    }
}

// ---------------- K7: pair MLP + sigmoid ----------------
__global__ void __launch_bounds__(128) k_mlp(
    const float* __restrict__ pooled, const float* __restrict__ Wm1,
    const float* __restrict__ bm1, const float* __restrict__ Wm2,
    const float* __restrict__ bm2, float* __restrict__ out) {
    __shared__ float pr[256];
    __shared__ float partial[2];
    int b = blockIdx.x, t = threadIdx.x;
    pr[t]       = pooled[(size_t)(2 * b) * 128 + t];
    pr[128 + t] = pooled[(size_t)(2 * b + 1) * 128 + t];
    __syncthreads();
    float acc = bm1[t];
    #pragma unroll 4
    for (int k = 0; k < 256; ++k) acc += pr[k] * Wm1[k * 128 + t];
    float h = acc > 0.f ? acc : 0.f;
    float v = h * Wm2[t];
    #pragma unroll
    for (int o = 32; o > 0; o >>= 1) v += __shfl_xor(v, o);
    if ((t & 63) == 0) partial[t >> 6] = v;
    __syncthreads();
    if (t == 0) {
        float z = partial[0] + partial[1] + bm2[0];
        out[b] = 1.f / (1.f + expf(-z));
    }
}

extern "C" void kernel_launch(void* const* d_in, const int* in_sizes, int n_in,
                              void* d_out, int out_size, void* d_ws, size_t ws_size,
                              hipStream_t stream) {
    const float* x     = (const float*)d_in[0];
    const int*   edge  = (const int*)d_in[1];
    const int*   ptr   = (const int*)d_in[2];
    const int*   split = (const int*)d_in[3];
    const float* W1  = (const float*)d_in[4];
    const float* b1  = (const float*)d_in[5];
    const float* W2  = (const float*)d_in[6];
    const float* b2  = (const float*)d_in[7];
    const float* Wm1 = (const float*)d_in[8];
    const float* bm1 = (const float*)d_in[9];
    const float* Wm2 = (const float*)d_in[10];
    const float* bm2 = (const float*)d_in[11];
    float* out = (float*)d_out;

    const int N    = in_sizes[0] / NF;     // 131072 nodes
    const int E    = in_sizes[1] / 2;      // 1048576 edges
    const int nB   = in_sizes[2] - 1;      // 2048 graphs
    const int nseg = 2 * nB;               // 4096 segments

    // workspace layout
    char* ws = (char*)d_ws;
    float*    Adj      = (float*)ws;                                   // nseg*1024 f32 (16 MB)
    size_t    offA     = (size_t)nseg * 1024 * sizeof(float);
    float*    deg      = (float*)(ws + offA);                          // N f32 (dinv after K3)
    unsigned* segloc   = (unsigned*)(ws + offA + (size_t)N * 4);
    int*      segstart = (int*)(ws + offA + (size_t)N * 8);
    int*      segcnt   = (int*)(ws + offA + (size_t)N * 8 + (size_t)nseg * 4);
    float*    pooled   = (float*)(ws + offA + (size_t)N * 8 + (size_t)nseg * 8);

    const int* srcp = edge;       // edge_index row 0
    const int* dstp = edge + E;   // edge_index row 1

    hipMemsetAsync(Adj, 0, offA, stream);
    k_segtab<<<(nseg + 255) / 256, 256, 0, stream>>>(ptr, split, nseg, segstart, segcnt);
    k_node<<<(N + 255) / 256, 256, 0, stream>>>(ptr, split, nB, N, segloc, deg);
    k_deg<<<(E + 255) / 256, 256, 0, stream>>>(srcp, dstp, E, segloc, deg);
    k_dinv<<<(N + 255) / 256, 256, 0, stream>>>(N, deg, segloc, Adj);
    k_adj<<<(E + 255) / 256, 256, 0, stream>>>(srcp, dstp, E, segloc, deg, Adj);
    k_gcn<<<nseg, 256, 0, stream>>>(x, Adj, segstart, segcnt, W1, b1, W2, b2, pooled);
    k_mlp<<<nB, 128, 0, stream>>>(pooled, Wm1, bm1, Wm2, bm2, out);
}

// Round 2
// 348.686 us; speedup vs baseline: 3.2994x; 3.2994x over previous
//
#include <hip/hip_runtime.h>
#include <math.h>

#define NF 128

typedef short bf16x8 __attribute__((ext_vector_type(8)));
typedef float f32x4  __attribute__((ext_vector_type(4)));

__device__ __forceinline__ unsigned short f2bf(float f) {
    unsigned int x = __float_as_uint(f);
    x += 0x7fff + ((x >> 16) & 1);      // RNE
    return (unsigned short)(x >> 16);
}
__device__ __forceinline__ float bf2f(unsigned short u) {
    return __uint_as_float(((unsigned int)u) << 16);
}
// swizzled LDS element index (bf16 elements), G4 XOR swizzle: rows spread across banks
__device__ __forceinline__ int xt_idx(int f, int c) { return (f * 128 + c) ^ ((f & 7) << 3); }
__device__ __forceinline__ int zb_idx(int m, int k) { return (m * 128 + k) ^ ((m & 7) << 3); }

// ---------------- K0: per-segment start/count table ----------------
__global__ void k_segtab(const int* __restrict__ ptr, const int* __restrict__ split,
                         int nseg, int* __restrict__ segstart, int* __restrict__ segcnt) {
    int s = blockIdx.x * blockDim.x + threadIdx.x;
    if (s >= nseg) return;
    int g = s >> 1;
    int base = ptr[g];
    int sp = split[g];
    segstart[s] = (s & 1) ? base + sp : base;
    segcnt[s]   = (s & 1) ? (ptr[g + 1] - base - sp) : sp;
}

// ---------------- K1: per-node (seg,loc) + deg init ----------------
__global__ void k_node(const int* __restrict__ ptr, const int* __restrict__ split,
                       int nB, int N, unsigned* __restrict__ segloc, float* __restrict__ deg) {
    int i = blockIdx.x * blockDim.x + threadIdx.x;
    if (i >= N) return;
    int lo = 0, hi = nB + 1;
    while (lo < hi) { int mid = (lo + hi) >> 1; if (ptr[mid] <= i) lo = mid + 1; else hi = mid; }
    int g = lo - 1;
    int local = i - ptr[g];
    int sp = split[g];
    int drug = (local >= sp) ? 1 : 0;
    int seg = 2 * g + drug;
    int loc = local - (drug ? sp : 0);
    segloc[i] = ((unsigned)seg << 8) | (unsigned)loc;
    deg[i] = 1.0f;   // self-loop
}

// ---------------- K2: degree accumulation ----------------
__global__ void k_deg(const int* __restrict__ src, const int* __restrict__ dst, int E,
                      const unsigned* __restrict__ segloc, float* __restrict__ deg) {
    int e = blockIdx.x * blockDim.x + threadIdx.x;
    if (e >= E) return;
    int s = src[e], d = dst[e];
    if ((segloc[s] >> 8) == (segloc[d] >> 8)) atomicAdd(&deg[d], 1.0f);
}

// ---------------- K3: dinv (in-place) + adjacency diagonal ----------------
__global__ void k_dinv(int N, float* __restrict__ deg, const unsigned* __restrict__ segloc,
                       float* __restrict__ A) {
    int i = blockIdx.x * blockDim.x + threadIdx.x;
    if (i >= N) return;
    float dv = rsqrtf(deg[i]);
    deg[i] = dv;
    unsigned sl = segloc[i];
    int seg = (int)(sl >> 8), loc = (int)(sl & 255u);
    A[(size_t)seg * 1024 + loc * 32 + loc] = dv * dv;
}

// ---------------- K5: adjacency off-diagonal (atomic) ----------------
// A[dst_local][src_local] per segment
__global__ void k_adj(const int* __restrict__ src, const int* __restrict__ dst, int E,
                      const unsigned* __restrict__ segloc, const float* __restrict__ dinv,
                      float* __restrict__ A) {
    int e = blockIdx.x * blockDim.x + threadIdx.x;
    if (e >= E) return;
    int s = src[e], d = dst[e];
    unsigned ss = segloc[s], dd = segloc[d];
    if ((ss >> 8) != (dd >> 8)) return;
    float n = dinv[s] * dinv[d];
    atomicAdd(&A[(size_t)(ss >> 8) * 1024 + (int)(dd & 255u) * 32 + (int)(ss & 255u)], n);
}

// ---------------- K_wt: transpose W1,W2 -> bf16 [fout][fin] ----------------
__global__ void k_wt(const float* __restrict__ W1, const float* __restrict__ W2,
                     short* __restrict__ Wt1, short* __restrict__ Wt2) {
    int n = blockIdx.x, k = threadIdx.x;
    Wt1[n * 128 + k] = (short)f2bf(W1[k * 128 + n]);
    Wt2[n * 128 + k] = (short)f2bf(W2[k * 128 + n]);
}

// ---------------- K6: fused 2-layer GCN + mean pool, MFMA bf16 ----------------
// One block = 4 segments = 128 nodes. H = relu((A_s X) W + b) per layer, then pool.
__global__ void __launch_bounds__(256, 2) k_gcn2(
    const float* __restrict__ x, const float* __restrict__ Adj,
    const int* __restrict__ segstart, const int* __restrict__ segcnt,
    const short* __restrict__ Wt1, const float* __restrict__ b1,
    const short* __restrict__ Wt2, const float* __restrict__ b2,
    float* __restrict__ pooled, int nseg)
{
    __shared__ short xt[128 * 128];        // feat-major [feat][node], swizzled
    __shared__ short zb[128 * 128];        // node-major [node][feat], swizzled
    __shared__ short ab[4 * 32 * 40];      // A row-major [dst][src], stride 40

    const int t  = threadIdx.x;
    const int w  = t >> 6;          // wave 0..3 -> segment w of this block
    const int l  = t & 63;
    const int fr = l & 15;
    const int g  = l >> 4;
    const int seg0 = blockIdx.x * 4;

    // ---- Adj (fp32) -> ab (bf16)
    for (int i = t; i < 4096; i += 256) {
        int s = i >> 10, rc = i & 1023;
        float v = (seg0 + s < nseg) ? Adj[((size_t)(seg0 + s) << 10) + rc] : 0.f;
        ab[s * 1280 + (rc >> 5) * 40 + (rc & 31)] = (short)f2bf(v);
    }
    // ---- X (fp32 node-major) -> xt (bf16 feat-major, swizzled), zero-pad invalid
    for (int idx = t; idx < 4096; idx += 256) {
        int c4 = idx & 31, j = idx >> 5;          // j = block-local node column
        int s = seg0 + (j >> 5);
        int loc = j & 31;
        float4 v = make_float4(0.f, 0.f, 0.f, 0.f);
        if (s < nseg && loc < segcnt[s])
            v = *reinterpret_cast<const float4*>(x + (size_t)(segstart[s] + loc) * NF + c4 * 4);
        int f0 = c4 * 4;
        xt[xt_idx(f0 + 0, j)] = (short)f2bf(v.x);
        xt[xt_idx(f0 + 1, j)] = (short)f2bf(v.y);
        xt[xt_idx(f0 + 2, j)] = (short)f2bf(v.z);
        xt[xt_idx(f0 + 3, j)] = (short)f2bf(v.w);
    }
    __syncthreads();

    #pragma unroll 1
    for (int layer = 0; layer < 2; ++layer) {
        const short* Wt = layer ? Wt2 : Wt1;
        const float* bb = layer ? b2  : b1;

        // ---- Z_s = A_s @ X_s, computed transposed: Zt = Xt @ A^T (per wave's segment)
        // A-frag: Xt[mt*16+fr][w*32 + g*8 + j]; B-frag: A[n=nt*16+fr][k=g*8+j]
        {
            bf16x8 bfr0 = *(const bf16x8*)&ab[w * 1280 + fr * 40 + g * 8];
            bf16x8 bfr1 = *(const bf16x8*)&ab[w * 1280 + (16 + fr) * 40 + g * 8];
            #pragma unroll
            for (int mt = 0; mt < 8; ++mt) {
                bf16x8 af = *(const bf16x8*)&xt[xt_idx(mt * 16 + fr, w * 32 + g * 8)];
                f32x4 z0 = {0.f, 0.f, 0.f, 0.f};
                f32x4 z1 = {0.f, 0.f, 0.f, 0.f};
                z0 = __builtin_amdgcn_mfma_f32_16x16x32_bf16(af, bfr0, z0, 0, 0, 0);
                z1 = __builtin_amdgcn_mfma_f32_16x16x32_bf16(af, bfr1, z1, 0, 0, 0);
                // C layout: col = fr (dst node), rows = mt*16 + g*4 + reg (feat) -> write node-major
                int fb = mt * 16 + g * 4;
                short4 p0, p1;
                p0.x = (short)f2bf(z0[0]); p0.y = (short)f2bf(z0[1]);
                p0.z = (short)f2bf(z0[2]); p0.w = (short)f2bf(z0[3]);
                p1.x = (short)f2bf(z1[0]); p1.y = (short)f2bf(z1[1]);
                p1.z = (short)f2bf(z1[2]); p1.w = (short)f2bf(z1[3]);
                *(short4*)&zb[zb_idx(w * 32 + fr,      fb)] = p0;
                *(short4*)&zb[zb_idx(w * 32 + 16 + fr, fb)] = p1;
            }
        }
        __syncthreads();

        // ---- H = relu(Z @ W + b): M=128 nodes (wave w: rows w*32..w*32+31), N=128, K=128
        {
            f32x4 acc[2][8];
            #pragma unroll
            for (int i = 0; i < 2; ++i)
                #pragma unroll
                for (int j = 0; j < 8; ++j) acc[i][j] = (f32x4){0.f, 0.f, 0.f, 0.f};
            #pragma unroll
            for (int kk = 0; kk < 4; ++kk) {
                bf16x8 a0 = *(const bf16x8*)&zb[zb_idx(w * 32 + fr,      kk * 32 + g * 8)];
                bf16x8 a1 = *(const bf16x8*)&zb[zb_idx(w * 32 + 16 + fr, kk * 32 + g * 8)];
                #pragma unroll
                for (int nt = 0; nt < 8; ++nt) {
                    bf16x8 wf = *(const bf16x8*)&Wt[(nt * 16 + fr) * 128 + kk * 32 + g * 8];
                    acc[0][nt] = __builtin_amdgcn_mfma_f32_16x16x32_bf16(a0, wf, acc[0][nt], 0, 0, 0);
                    acc[1][nt] = __builtin_amdgcn_mfma_f32_16x16x32_bf16(a1, wf, acc[1][nt], 0, 0, 0);
                }
            }
            // epilogue: +bias, relu, bf16, write feat-major into xt (xt readers all done)
            #pragma unroll
            for (int nt = 0; nt < 8; ++nt) {
                int fout = nt * 16 + fr;
                float bv = bb[fout];
                #pragma unroll
                for (int mt = 0; mt < 2; ++mt) {
                    int n0 = w * 32 + mt * 16 + g * 4;   // 4 consecutive nodes
                    short4 p;
                    float v0 = acc[mt][nt][0] + bv; p.x = (short)f2bf(v0 > 0.f ? v0 : 0.f);
                    float v1 = acc[mt][nt][1] + bv; p.y = (short)f2bf(v1 > 0.f ? v1 : 0.f);
                    float v2 = acc[mt][nt][2] + bv; p.z = (short)f2bf(v2 > 0.f ? v2 : 0.f);
                    float v3 = acc[mt][nt][3] + bv; p.w = (short)f2bf(v3 > 0.f ? v3 : 0.f);
                    *(short4*)&xt[xt_idx(fout, n0)] = p;
                }
            }
        }
        __syncthreads();
    }

    // ---- mean pool per segment (H2 is in xt, feat-major)
    {
        int f = t & 127;
        for (int s = t >> 7; s < 4; s += 2) {
            int gs = seg0 + s;
            if (gs >= nseg) continue;
            int cnt = segcnt[gs];
            float sum = 0.f;
            for (int c = 0; c < cnt; ++c)
                sum += bf2f((unsigned short)xt[xt_idx(f, s * 32 + c)]);
            pooled[(size_t)gs * NF + f] = sum / (float)(cnt > 0 ? cnt : 1);
        }
    }
}

// ---------------- K7: pair MLP + sigmoid (fp32) ----------------
__global__ void __launch_bounds__(128) k_mlp(
    const float* __restrict__ pooled, const float* __restrict__ Wm1,
    const float* __restrict__ bm1, const float* __restrict__ Wm2,
    const float* __restrict__ bm2, float* __restrict__ out) {
    __shared__ float pr[256];
    __shared__ float partial[2];
    int b = blockIdx.x, t = threadIdx.x;
    pr[t]       = pooled[(size_t)(2 * b) * 128 + t];
    pr[128 + t] = pooled[(size_t)(2 * b + 1) * 128 + t];
    __syncthreads();
    float acc = bm1[t];
    #pragma unroll 4
    for (int k = 0; k < 256; ++k) acc += pr[k] * Wm1[k * 128 + t];
    float h = acc > 0.f ? acc : 0.f;
    float v = h * Wm2[t];
    #pragma unroll
    for (int o = 32; o > 0; o >>= 1) v += __shfl_xor(v, o);
    if ((t & 63) == 0) partial[t >> 6] = v;
    __syncthreads();
    if (t == 0) {
        float z = partial[0] + partial[1] + bm2[0];
        out[b] = 1.f / (1.f + expf(-z));
    }
}

extern "C" void kernel_launch(void* const* d_in, const int* in_sizes, int n_in,
                              void* d_out, int out_size, void* d_ws, size_t ws_size,
                              hipStream_t stream) {
    const float* x     = (const float*)d_in[0];
    const int*   edge  = (const int*)d_in[1];
    const int*   ptr   = (const int*)d_in[2];
    const int*   split = (const int*)d_in[3];
    const float* W1  = (const float*)d_in[4];
    const float* b1  = (const float*)d_in[5];
    const float* W2  = (const float*)d_in[6];
    const float* b2  = (const float*)d_in[7];
    const float* Wm1 = (const float*)d_in[8];
    const float* bm1 = (const float*)d_in[9];
    const float* Wm2 = (const float*)d_in[10];
    const float* bm2 = (const float*)d_in[11];
    float* out = (float*)d_out;

    const int N    = in_sizes[0] / NF;     // 131072 nodes
    const int E    = in_sizes[1] / 2;      // 1048576 edges
    const int nB   = in_sizes[2] - 1;      // 2048 graphs
    const int nseg = 2 * nB;               // 4096 segments

    // workspace layout
    char* ws = (char*)d_ws;
    size_t off = 0;
    float*    Adj      = (float*)(ws + off);  size_t adjb = (size_t)nseg * 1024 * 4; off += adjb;
    float*    deg      = (float*)(ws + off);  off += (size_t)N * 4;
    unsigned* segloc   = (unsigned*)(ws + off); off += (size_t)N * 4;
    int*      segstart = (int*)(ws + off);    off += (size_t)nseg * 4;
    int*      segcnt   = (int*)(ws + off);    off += (size_t)nseg * 4;
    float*    pooled   = (float*)(ws + off);  off += (size_t)nseg * 128 * 4;
    short*    Wt1      = (short*)(ws + off);  off += 128 * 128 * 2;
    short*    Wt2      = (short*)(ws + off);  off += 128 * 128 * 2;

    const int* srcp = edge;
    const int* dstp = edge + E;

    hipMemsetAsync(Adj, 0, adjb, stream);
    k_segtab<<<(nseg + 255) / 256, 256, 0, stream>>>(ptr, split, nseg, segstart, segcnt);
    k_node<<<(N + 255) / 256, 256, 0, stream>>>(ptr, split, nB, N, segloc, deg);
    k_deg<<<(E + 255) / 256, 256, 0, stream>>>(srcp, dstp, E, segloc, deg);
    k_dinv<<<(N + 255) / 256, 256, 0, stream>>>(N, deg, segloc, Adj);
    k_adj<<<(E + 255) / 256, 256, 0, stream>>>(srcp, dstp, E, segloc, deg, Adj);
    k_wt<<<128, 128, 0, stream>>>(W1, W2, Wt1, Wt2);
    k_gcn2<<<(nseg + 3) / 4, 256, 0, stream>>>(x, Adj, segstart, segcnt,
                                               Wt1, b1, Wt2, b2, pooled, nseg);
    k_mlp<<<nB, 128, 0, stream>>>(pooled, Wm1, bm1, Wm2, bm2, out);
}